// Round 10
// baseline (240.604 us; speedup 1.0000x reference)
//
#include <hip/hip_runtime.h>
#include <stddef.h>

#define SEQ_LEN 64
#define BATCH   262144
#define ROW4    (BATCH / 2)   // float4 elements per timestep row (2 batch elems each)
#define G       8             // double-buffer group depth

// One Anki scheduler step, exactly mirroring the JAX reference arithmetic.
// `first` == jnp.all(state == 0): globally true only at t==0 (ease >= 1.3
// afterwards makes all-zero impossible).
__device__ __forceinline__ void anki_step(bool first, float dt, float rating,
                                          float& ivl, float& ease,
                                          float w0, float w1, float w2, float w3,
                                          float w4, float w5, float w6)
{
    float days_late = dt - ivl;
    float elapsed   = ivl + days_late;

    float m = fmaxf(elapsed * ease, ivl);
    float early = (rating == 2.0f) ? fmaxf(elapsed * w4, ivl * w4 * 0.5f)
                : (rating == 4.0f) ? m
                :                    m * (w3 - (w3 - 1.0f) * 0.5f);

    float nonearly = (rating == 2.0f) ? ivl * w4
                   : (rating == 4.0f) ? (ivl + days_late * 0.5f) * ease
                   :                    (ivl + days_late) * ease * w3;

    float upd_ivl = (rating == 1.0f) ? ivl * w5
                  : ((days_late < 0.0f) ? early : nonearly) * w6;

    float upd_ease = (rating == 1.0f) ? ease - 0.2f
                   : (rating == 2.0f) ? ease - 0.15f
                   : (rating == 4.0f) ? ease + 0.15f
                   :                    ease;

    float init_ivl = (rating < 4.0f) ? w0 : w1;

    float ni = first ? init_ivl : upd_ivl;
    float ne = first ? w2       : upd_ease;

    ne = fminf(fmaxf(ne, 1.3f), 5.5f);

    float x  = ni - 1.0f;
    float lr = (x >= 0.0f) ? x : 0.01f * x;     // leaky_relu slope 0.01
    ni = fminf(fmaxf(fmaxf(lr + 1.0f, ni), 0.01f), 36500.0f);

    ivl  = ni;
    ease = ne;
}

// __launch_bounds__(256, 1): grid caps occupancy at ~2 waves/SIMD regardless,
// so give the register allocator the full budget — round 4 proved that the
// default (max-occupancy) target collapses the double buffer to VGPR=28 and
// serializes every load. The 16 float4 buffers need ~64 VGPRs minimum.
__global__ __launch_bounds__(256, 1)
void anki_scan(const float4* __restrict__ in, const float* __restrict__ w,
               float4* __restrict__ out)
{
    const int b = blockIdx.x * 256 + threadIdx.x;   // one float4 = 2 batch elems

    const float w0 = w[0], w1 = w[1], w2 = w[2], w3 = w[3],
                w4 = w[4], w5 = w[5], w6 = w[6];

    float i0 = 0.0f, e0 = 0.0f, i1 = 0.0f, e1 = 0.0f;   // two state chains

    // Prologue: group 0 in flight together.
    float4 buf[G];
    #pragma unroll
    for (int i = 0; i < G; ++i)
        buf[i] = in[(size_t)i * ROW4 + b];

    // Steady state: issue group g+1's 8 loads, compute group g from registers,
    // rotate. All indices compile-time constants inside the unrolled loops ->
    // everything stays in registers. Compute time per iteration (~960 cy)
    // covers one HBM latency, so the copy-point wait is ~zero.
    #pragma unroll 1
    for (int g = 0; g < SEQ_LEN / G - 1; ++g) {
        float4 nxt[G];
        #pragma unroll
        for (int i = 0; i < G; ++i)
            nxt[i] = in[(size_t)((g + 1) * G + i) * ROW4 + b];

        #pragma unroll
        for (int i = 0; i < G; ++i) {
            const bool first = (g == 0) && (i == 0);
            anki_step(first, buf[i].x, buf[i].y, i0, e0, w0, w1, w2, w3, w4, w5, w6);
            anki_step(first, buf[i].z, buf[i].w, i1, e1, w0, w1, w2, w3, w4, w5, w6);
            out[(size_t)(g * G + i) * ROW4 + b] = make_float4(i0, e0, i1, e1);
        }

        #pragma unroll
        for (int i = 0; i < G; ++i) buf[i] = nxt[i];
    }

    // Last group (no prefetch).
    #pragma unroll
    for (int i = 0; i < G; ++i) {
        anki_step(false, buf[i].x, buf[i].y, i0, e0, w0, w1, w2, w3, w4, w5, w6);
        anki_step(false, buf[i].z, buf[i].w, i1, e1, w0, w1, w2, w3, w4, w5, w6);
        out[(size_t)(SEQ_LEN - G + i) * ROW4 + b] = make_float4(i0, e0, i1, e1);
    }

    // final_state row, appended after the (64, B, 2) outputs
    out[(size_t)SEQ_LEN * ROW4 + b] = make_float4(i0, e0, i1, e1);
}

extern "C" void kernel_launch(void* const* d_in, const int* in_sizes, int n_in,
                              void* d_out, int out_size, void* d_ws, size_t ws_size,
                              hipStream_t stream)
{
    const float4* in  = (const float4*)d_in[0];  // (64, 262144, 2) f32
    const float*  w   = (const float*)d_in[1];   // (7,) f32
    float4*       out = (float4*)d_out;          // (64,B,2) ++ (B,2)

    anki_scan<<<ROW4 / 256, 256, 0, stream>>>(in, w, out);
}